// Round 1
// baseline (1223.059 us; speedup 1.0000x reference)
//
#include <hip/hip_runtime.h>

#define H   128
#define NB  4      // bases
#define BM  128    // GEMM M-tile
#define BK  32     // GEMM K-chunk

// ---------------- zero fill ----------------
__global__ __launch_bounds__(256) void zero_f4(float4* __restrict__ p, int n4) {
    int i = blockIdx.x * 256 + threadIdx.x;
    if (i < n4) p[i] = make_float4(0.f, 0.f, 0.f, 0.f);
}

// ---------------- GEMM: Hb[b] = h @ basis[b]  (M x 128 @ 128 x 128) ----------------
// grid: (ceil(M/BM), 1, NB), block 256. 8x8 register tile per thread.
__global__ __launch_bounds__(256) void gemm_basis(
        const float* __restrict__ h, const float* __restrict__ basis,
        float* __restrict__ Hb, int M) {
    __shared__ float As[BK][BM + 4];   // transposed A: As[k][m]
    __shared__ float Bs[BK][H + 4];    // Bs[k][o]

    const int b  = blockIdx.z;
    const int m0 = blockIdx.x * BM;
    const float* Bsrc = basis + (size_t)b * H * H;
    const int tid = threadIdx.x;
    const int tx  = tid & 15;    // output-col group
    const int ty  = tid >> 4;    // output-row group

    float acc[8][8];
#pragma unroll
    for (int i = 0; i < 8; ++i)
#pragma unroll
        for (int j = 0; j < 8; ++j) acc[i][j] = 0.f;

    for (int k0 = 0; k0 < H; k0 += BK) {
        // load A chunk (BM x BK), store transposed into LDS
#pragma unroll
        for (int r = 0; r < 4; ++r) {
            int id  = tid + r * 256;       // 0..1023
            int row = id >> 3;             // 0..127
            int kf  = id & 7;              // float4 idx within BK
            int m   = m0 + row;
            float4 v = make_float4(0.f, 0.f, 0.f, 0.f);
            if (m < M) v = *(const float4*)(h + (size_t)m * H + k0 + kf * 4);
            As[kf * 4 + 0][row] = v.x;
            As[kf * 4 + 1][row] = v.y;
            As[kf * 4 + 2][row] = v.z;
            As[kf * 4 + 3][row] = v.w;
        }
        // load B chunk (BK x H)
#pragma unroll
        for (int r = 0; r < 4; ++r) {
            int id = tid + r * 256;
            int k  = id >> 5;              // 0..31
            int nf = id & 31;              // float4 idx within H
            float4 v = *(const float4*)(Bsrc + (size_t)(k0 + k) * H + nf * 4);
            *(float4*)&Bs[k][nf * 4] = v;
        }
        __syncthreads();

#pragma unroll
        for (int k = 0; k < BK; ++k) {
            float4 a0 = *(const float4*)&As[k][ty * 8];
            float4 a1 = *(const float4*)&As[k][ty * 8 + 4];
            float4 b0 = *(const float4*)&Bs[k][tx * 8];
            float4 b1 = *(const float4*)&Bs[k][tx * 8 + 4];
            float av[8] = {a0.x, a0.y, a0.z, a0.w, a1.x, a1.y, a1.z, a1.w};
            float bv[8] = {b0.x, b0.y, b0.z, b0.w, b1.x, b1.y, b1.z, b1.w};
#pragma unroll
            for (int i = 0; i < 8; ++i)
#pragma unroll
                for (int j = 0; j < 8; ++j)
                    acc[i][j] = fmaf(av[i], bv[j], acc[i][j]);
        }
        __syncthreads();
    }

    float* C = Hb + (size_t)b * M * H;
#pragma unroll
    for (int i = 0; i < 8; ++i) {
        int m = m0 + ty * 8 + i;
        if (m < M) {
            float4 v0 = make_float4(acc[i][0], acc[i][1], acc[i][2], acc[i][3]);
            float4 v1 = make_float4(acc[i][4], acc[i][5], acc[i][6], acc[i][7]);
            *(float4*)(C + (size_t)m * H + tx * 8)     = v0;
            *(float4*)(C + (size_t)m * H + tx * 8 + 4) = v1;
        }
    }
}

// ---------------- edge scatter: agg[dst] += norm * sum_b comp[et,b]*Hb[b][src] ----
// one 64-lane wave per edge; lane handles 2 consecutive floats (float2 = 512B/wave)
__global__ __launch_bounds__(256) void edge_scatter(
        const float* __restrict__ Hb, const int* __restrict__ src,
        const int* __restrict__ dst, const int* __restrict__ etype,
        const float* __restrict__ norm, const float* __restrict__ comp,
        float* __restrict__ agg, int E, int M) {
    int e = blockIdx.x * 4 + (threadIdx.x >> 6);
    if (e >= E) return;
    int lane = threadIdx.x & 63;

    int s = src[e];
    int d = dst[e];
    int r = etype[e];
    float w = norm[e];
    float c0 = comp[r * NB + 0];
    float c1 = comp[r * NB + 1];
    float c2 = comp[r * NB + 2];
    float c3 = comp[r * NB + 3];

    size_t stride = (size_t)M * H;
    size_t base   = (size_t)s * H + lane * 2;
    float2 v0 = *(const float2*)(Hb + base);
    float2 v1 = *(const float2*)(Hb + base + stride);
    float2 v2 = *(const float2*)(Hb + base + 2 * stride);
    float2 v3 = *(const float2*)(Hb + base + 3 * stride);

    float x = (c0 * v0.x + c1 * v1.x + c2 * v2.x + c3 * v3.x) * w;
    float y = (c0 * v0.y + c1 * v1.y + c2 * v2.y + c3 * v3.y) * w;

    float* out = agg + (size_t)d * H + lane * 2;
    atomicAdd(out,     x);
    atomicAdd(out + 1, y);
}

// ---------------- bias + relu (elementwise, in-place capable) ----------------
__global__ __launch_bounds__(256) void bias_relu(
        const float* __restrict__ in, const float* __restrict__ bias,
        float* __restrict__ out, int n4) {
    int i = blockIdx.x * 256 + threadIdx.x;
    if (i >= n4) return;
    float4 v = ((const float4*)in)[i];
    float4 b = ((const float4*)bias)[i & 31];   // H=128 -> 32 float4 per row
    v.x = fmaxf(v.x + b.x, 0.f);
    v.y = fmaxf(v.y + b.y, 0.f);
    v.z = fmaxf(v.z + b.z, 0.f);
    v.w = fmaxf(v.w + b.w, 0.f);
    ((float4*)out)[i] = v;
}

extern "C" void kernel_launch(void* const* d_in, const int* in_sizes, int n_in,
                              void* d_out, int out_size, void* d_ws, size_t ws_size,
                              hipStream_t stream) {
    const float* feats  = (const float*)d_in[0];
    const int*   src    = (const int*)  d_in[1];
    const int*   dst    = (const int*)  d_in[2];
    const int*   etype  = (const int*)  d_in[3];
    const float* norm   = (const float*)d_in[4];
    const float* basis0 = (const float*)d_in[5];
    const float* comp0  = (const float*)d_in[6];
    const float* bias0  = (const float*)d_in[7];
    const float* basis1 = (const float*)d_in[8];
    const float* comp1  = (const float*)d_in[9];
    const float* bias1  = (const float*)d_in[10];
    float* out = (float*)d_out;

    const int M = in_sizes[0] / H;     // 50000
    const int E = in_sizes[1];         // 600000

    float* Hb  = (float*)d_ws;                      // NB*M*H floats (102.4 MB)
    float* agg = Hb + (size_t)NB * M * H;           // M*H floats (25.6 MB)

    const int n4 = M * H / 4;
    dim3 gemm_grid((M + BM - 1) / BM, 1, NB);
    dim3 blk(256);
    int zb = (n4 + 255) / 256;
    int eb = (E + 3) / 4;

    // ---- layer 0: h1 = relu(scatter(edges, feats@basis0 · comp0) + bias0) ----
    gemm_basis  <<<gemm_grid, blk, 0, stream>>>(feats, basis0, Hb, M);
    zero_f4     <<<zb, blk, 0, stream>>>((float4*)agg, n4);
    edge_scatter<<<eb, blk, 0, stream>>>(Hb, src, dst, etype, norm, comp0, agg, E, M);
    bias_relu   <<<zb, blk, 0, stream>>>(agg, bias0, agg, n4);

    // ---- layer 1: out = relu(scatter(edges, h1@basis1 · comp1) + bias1) ----
    gemm_basis  <<<gemm_grid, blk, 0, stream>>>(agg, basis1, Hb, M);
    zero_f4     <<<zb, blk, 0, stream>>>((float4*)out, n4);
    edge_scatter<<<eb, blk, 0, stream>>>(Hb, src, dst, etype, norm, comp1, out, E, M);
    bias_relu   <<<zb, blk, 0, stream>>>(out, bias1, out, n4);
}

// Round 2
// 328.756 us; speedup vs baseline: 3.7203x; 3.7203x over previous
//
#include <hip/hip_runtime.h>

#define H    128
#define NB   4
#define NR   8

typedef __attribute__((ext_vector_type(8))) short short8;
typedef __attribute__((ext_vector_type(4))) float f32x4;

static __device__ __forceinline__ unsigned short f2bf(float f) {
    unsigned u = __float_as_uint(f);
    unsigned r = (u + 0x7fffu + ((u >> 16) & 1u)) >> 16;
    return (unsigned short)r;
}
static __device__ __forceinline__ float bf_lo(unsigned v) {
    return __uint_as_float((v & 0xffffu) << 16);
}
static __device__ __forceinline__ float bf_hi(unsigned v) {
    return __uint_as_float(v & 0xffff0000u);
}

// ---------------- zero int array ----------------
__global__ __launch_bounds__(256) void zero_i(int* __restrict__ p, int n) {
    int i = blockIdx.x * 256 + threadIdx.x;
    if (i < n) p[i] = 0;
}

// ---------------- degree histogram ----------------
__global__ __launch_bounds__(256) void hist_dst(const int* __restrict__ dst,
                                                int* __restrict__ counts, int E) {
    int e = blockIdx.x * 256 + threadIdx.x;
    if (e < E) atomicAdd(&counts[dst[e]], 1);
}

// ---------------- single-block exclusive scan -> offsets[n+1] ----------------
__global__ __launch_bounds__(1024) void scan_offsets(const int* __restrict__ counts,
                                                     int* __restrict__ offs, int n) {
    __shared__ int buf[1024];
    __shared__ int carry_s;
    int tid = threadIdx.x;
    if (tid == 0) { carry_s = 0; offs[0] = 0; }
    __syncthreads();
    for (int base = 0; base < n; base += 1024) {
        int i = base + tid;
        int v = (i < n) ? counts[i] : 0;
        buf[tid] = v;
        __syncthreads();
        for (int off = 1; off < 1024; off <<= 1) {
            int t = (tid >= off) ? buf[tid - off] : 0;
            __syncthreads();
            buf[tid] += t;
            __syncthreads();
        }
        int c = carry_s;
        if (i < n) offs[i + 1] = c + buf[tid];
        __syncthreads();
        if (tid == 1023) carry_s = c + buf[1023];
        __syncthreads();
    }
}

// ---------------- scatter edges into CSR order ----------------
__global__ __launch_bounds__(256) void scatter_edges(
        const int* __restrict__ src, const int* __restrict__ dst,
        const int* __restrict__ etype, const float* __restrict__ norm,
        const int* __restrict__ offs, int* __restrict__ counts,
        int* __restrict__ ridx, float* __restrict__ rnorm, int E, int M) {
    int e = blockIdx.x * 256 + threadIdx.x;
    if (e >= E) return;
    int d = dst[e];
    int pos = offs[d] + atomicSub(&counts[d], 1) - 1;
    ridx[pos]  = etype[e] * M + src[e];
    rnorm[pos] = norm[e];
}

// ---------------- f32 -> bf16 convert ----------------
__global__ __launch_bounds__(256) void convert_bf16(const float* __restrict__ in,
                                                    unsigned short* __restrict__ out, int n4) {
    int i = blockIdx.x * 256 + threadIdx.x;
    if (i >= n4) return;
    float4 v = ((const float4*)in)[i];
    ushort4 o;
    o.x = f2bf(v.x); o.y = f2bf(v.y); o.z = f2bf(v.z); o.w = f2bf(v.w);
    ((ushort4*)out)[i] = o;
}

// ---------------- W^T build: Wt[l][r][o][d] = bf16(sum_b comp[r,b]*basis[b][d][o]) ----
__global__ __launch_bounds__(128) void make_wt(
        const float* __restrict__ basis0, const float* __restrict__ comp0,
        const float* __restrict__ basis1, const float* __restrict__ comp1,
        unsigned short* __restrict__ Wt) {
    int r = blockIdx.x;        // 0..7
    int d = blockIdx.y;        // 0..127
    int l = blockIdx.z;        // 0..1
    int o = threadIdx.x;       // 0..127
    const float* basis = l ? basis1 : basis0;
    const float* comp  = l ? comp1  : comp0;
    float s = 0.f;
#pragma unroll
    for (int b = 0; b < NB; ++b)
        s += comp[r * NB + b] * basis[((size_t)b * H + d) * H + o];
    Wt[(((size_t)l * NR + r) * H + o) * H + d] = f2bf(s);
}

// ---------------- MFMA GEMM: Hr[r] = h @ W_r, bf16 in/out, f32 accum ----------------
// grid (ceil(M/128), 8), block 256 (4 waves). Full K=128 staged once.
__global__ __launch_bounds__(256) void gemm_hr(
        const unsigned short* __restrict__ hbf,  // [M][128] bf16
        const unsigned short* __restrict__ Wt,   // [8][128 o][128 d] bf16
        unsigned short* __restrict__ Hr,         // [8][M][128] bf16
        int M) {
    __shared__ unsigned short lA[128 * 128];
    __shared__ unsigned short lB[128 * 128];
    const int m0  = blockIdx.x * 128;
    const int rel = blockIdx.y;
    const int tid = threadIdx.x;

    // stage A (h tile, swizzled rows)
#pragma unroll
    for (int i = 0; i < 8; ++i) {
        int idx = tid + i * 256;      // 0..2047
        int row = idx >> 4;           // 0..127
        int c   = idx & 15;           // 16B chunk
        int gm  = m0 + row;
        if (gm < M) {
            short8 v = *(const short8*)(hbf + (size_t)gm * H + c * 8);
            int byte = row * 256 + ((c * 16) ^ ((row & 7) << 4));
            *(short8*)((char*)lA + byte) = v;
        }
    }
    // stage B (Wt[rel], swizzled rows; row index = output col o)
    const unsigned short* Wr = Wt + (size_t)rel * H * H;
#pragma unroll
    for (int i = 0; i < 8; ++i) {
        int idx = tid + i * 256;
        int row = idx >> 4;
        int c   = idx & 15;
        short8 v = *(const short8*)(Wr + (size_t)row * H + c * 8);
        int byte = row * 256 + ((c * 16) ^ ((row & 7) << 4));
        *(short8*)((char*)lB + byte) = v;
    }
    __syncthreads();

    const int wid  = tid >> 6;
    const int lane = tid & 63;
    const int lr   = lane & 15;
    const int lg   = lane >> 4;

    f32x4 acc[2][8];
#pragma unroll
    for (int m = 0; m < 2; ++m)
#pragma unroll
        for (int n = 0; n < 8; ++n) acc[m][n] = (f32x4){0.f, 0.f, 0.f, 0.f};

#pragma unroll
    for (int s = 0; s < 4; ++s) {
        short8 a[2], b[8];
        int kb = s * 64 + lg * 16;
#pragma unroll
        for (int m = 0; m < 2; ++m) {
            int row = wid * 32 + m * 16 + lr;
            a[m] = *(const short8*)((const char*)lA + row * 256 + (kb ^ ((row & 7) << 4)));
        }
#pragma unroll
        for (int n = 0; n < 8; ++n) {
            int col = n * 16 + lr;
            b[n] = *(const short8*)((const char*)lB + col * 256 + (kb ^ ((col & 7) << 4)));
        }
#pragma unroll
        for (int m = 0; m < 2; ++m)
#pragma unroll
            for (int n = 0; n < 8; ++n)
                acc[m][n] = __builtin_amdgcn_mfma_f32_16x16x32_bf16(a[m], b[n], acc[m][n], 0, 0, 0);
    }

    unsigned short* C = Hr + (size_t)rel * M * H;
#pragma unroll
    for (int m = 0; m < 2; ++m) {
#pragma unroll
        for (int j = 0; j < 4; ++j) {
            int row = m0 + wid * 32 + m * 16 + lg * 4 + j;
            if (row < M) {
#pragma unroll
                for (int n = 0; n < 8; ++n) {
                    int col = n * 16 + lr;
                    C[(size_t)row * H + col] = f2bf(acc[m][n][j]);
                }
            }
        }
    }
}

// ---------------- per-node aggregation (CSR), fused bias+relu ----------------
// one wave per dst node; lane covers cols [2*lane, 2*lane+1]
__global__ __launch_bounds__(256) void agg_nodes(
        const unsigned short* __restrict__ Hr,   // rows indexed by ridx, 128 bf16 each
        const int* __restrict__ offs, const int* __restrict__ ridx,
        const float* __restrict__ rnorm, const float* __restrict__ bias,
        void* __restrict__ outp, int M, int write_bf16) {
    int v = blockIdx.x * 4 + (threadIdx.x >> 6);
    if (v >= M) return;
    int lane = threadIdx.x & 63;
    int beg = offs[v], end = offs[v + 1];

    float ax = 0.f, ay = 0.f;
    for (int base = beg; base < end; base += 64) {
        int cnt = min(64, end - base);
        int myrow = 0; float myw = 0.f;
        if (lane < cnt) { myrow = ridx[base + lane]; myw = rnorm[base + lane]; }
        int j = 0;
        for (; j + 4 <= cnt; j += 4) {
            int r0 = __shfl(myrow, j);     float w0 = __shfl(myw, j);
            int r1 = __shfl(myrow, j + 1); float w1 = __shfl(myw, j + 1);
            int r2 = __shfl(myrow, j + 2); float w2 = __shfl(myw, j + 2);
            int r3 = __shfl(myrow, j + 3); float w3 = __shfl(myw, j + 3);
            unsigned v0 = *(const unsigned*)(Hr + (size_t)r0 * H + lane * 2);
            unsigned v1 = *(const unsigned*)(Hr + (size_t)r1 * H + lane * 2);
            unsigned v2 = *(const unsigned*)(Hr + (size_t)r2 * H + lane * 2);
            unsigned v3 = *(const unsigned*)(Hr + (size_t)r3 * H + lane * 2);
            ax += w0 * bf_lo(v0); ay += w0 * bf_hi(v0);
            ax += w1 * bf_lo(v1); ay += w1 * bf_hi(v1);
            ax += w2 * bf_lo(v2); ay += w2 * bf_hi(v2);
            ax += w3 * bf_lo(v3); ay += w3 * bf_hi(v3);
        }
        for (; j < cnt; ++j) {
            int r0 = __shfl(myrow, j); float w0 = __shfl(myw, j);
            unsigned v0 = *(const unsigned*)(Hr + (size_t)r0 * H + lane * 2);
            ax += w0 * bf_lo(v0); ay += w0 * bf_hi(v0);
        }
    }
    ax = fmaxf(ax + bias[lane * 2],     0.f);
    ay = fmaxf(ay + bias[lane * 2 + 1], 0.f);
    if (write_bf16) {
        unsigned short* o = (unsigned short*)outp + (size_t)v * H + lane * 2;
        unsigned pk = (unsigned)f2bf(ax) | ((unsigned)f2bf(ay) << 16);
        *(unsigned*)o = pk;
    } else {
        float* o = (float*)outp + (size_t)v * H + lane * 2;
        *(float2*)o = make_float2(ax, ay);
    }
}

extern "C" void kernel_launch(void* const* d_in, const int* in_sizes, int n_in,
                              void* d_out, int out_size, void* d_ws, size_t ws_size,
                              hipStream_t stream) {
    const float* feats  = (const float*)d_in[0];
    const int*   src    = (const int*)  d_in[1];
    const int*   dst    = (const int*)  d_in[2];
    const int*   etype  = (const int*)  d_in[3];
    const float* norm   = (const float*)d_in[4];
    const float* basis0 = (const float*)d_in[5];
    const float* comp0  = (const float*)d_in[6];
    const float* bias0  = (const float*)d_in[7];
    const float* basis1 = (const float*)d_in[8];
    const float* comp1  = (const float*)d_in[9];
    const float* bias1  = (const float*)d_in[10];
    float* out = (float*)d_out;

    const int M = in_sizes[0] / H;     // 50000
    const int E = in_sizes[1];         // 600000

    // workspace carve-up (256B aligned)
    char* ws = (char*)d_ws;
    size_t cur = 0;
    auto take = [&](size_t bytes) { void* p = ws + cur; cur += (bytes + 255) & ~(size_t)255; return p; };
    unsigned short* Hr   = (unsigned short*)take((size_t)NR * M * H * 2);  // 102.4 MB
    unsigned short* hbf  = (unsigned short*)take((size_t)M * H * 2);       // 12.8 MB (feats bf16, then h1 bf16)
    unsigned short* Wt   = (unsigned short*)take((size_t)2 * NR * H * H * 2); // 512 KB
    int*   counts = (int*)take((size_t)M * 4);
    int*   offs   = (int*)take((size_t)(M + 1) * 4);
    int*   ridx   = (int*)take((size_t)E * 4);
    float* rnorm  = (float*)take((size_t)E * 4);

    dim3 blk(256);
    int mb  = (M + 255) / 256;
    int eb  = (E + 255) / 256;
    int n4  = M * H / 4;
    int cb  = (n4 + 255) / 256;
    dim3 gemm_grid((M + 127) / 128, NR);
    int agg_blocks = (M + 3) / 4;

    // ---- one-time graph prep (every call: must be stateless) ----
    zero_i       <<<mb, blk, 0, stream>>>(counts, M);
    hist_dst     <<<eb, blk, 0, stream>>>(dst, counts, E);
    scan_offsets <<<1, 1024, 0, stream>>>(counts, offs, M);
    scatter_edges<<<eb, blk, 0, stream>>>(src, dst, etype, norm, offs, counts, ridx, rnorm, E, M);
    convert_bf16 <<<cb, blk, 0, stream>>>(feats, hbf, n4);
    make_wt      <<<dim3(NR, H, 2), 128, 0, stream>>>(basis0, comp0, basis1, comp1, Wt);

    // ---- layer 0 ----
    gemm_hr  <<<gemm_grid, blk, 0, stream>>>(hbf, Wt, Hr, M);
    agg_nodes<<<agg_blocks, blk, 0, stream>>>(Hr, offs, ridx, rnorm, bias0, hbf, M, 1);

    // ---- layer 1 ----
    gemm_hr  <<<gemm_grid, blk, 0, stream>>>(hbf, Wt + (size_t)NR * H * H, Hr, M);
    agg_nodes<<<agg_blocks, blk, 0, stream>>>(Hr, offs, ridx, rnorm, bias1, out, M, 0);
}

// Round 3
// 250.055 us; speedup vs baseline: 4.8912x; 1.3147x over previous
//
#include <hip/hip_runtime.h>

#define H    128
#define NB   4
#define NR   8

typedef __attribute__((ext_vector_type(8))) short short8;
typedef __attribute__((ext_vector_type(4))) float f32x4;

static __device__ __forceinline__ unsigned short f2bf(float f) {
    unsigned u = __float_as_uint(f);
    unsigned r = (u + 0x7fffu + ((u >> 16) & 1u)) >> 16;
    return (unsigned short)r;
}
static __device__ __forceinline__ float bf_lo(unsigned v) {
    return __uint_as_float((v & 0xffffu) << 16);
}
static __device__ __forceinline__ float bf_hi(unsigned v) {
    return __uint_as_float(v & 0xffff0000u);
}

// ---------------- zero int array ----------------
__global__ __launch_bounds__(256) void zero_i(int* __restrict__ p, int n) {
    int i = blockIdx.x * 256 + threadIdx.x;
    if (i < n) p[i] = 0;
}

// ---------------- degree histogram ----------------
__global__ __launch_bounds__(256) void hist_dst(const int* __restrict__ dst,
                                                int* __restrict__ counts, int E) {
    int e = blockIdx.x * 256 + threadIdx.x;
    if (e < E) atomicAdd(&counts[dst[e]], 1);
}

// ---------------- hierarchical scan, stage 1: per-block inclusive scan ----------------
__global__ __launch_bounds__(1024) void scan_blocks(const int* __restrict__ counts,
                                                    int* __restrict__ partial,
                                                    int* __restrict__ blocksums, int n) {
    __shared__ int buf[1024];
    int tid = threadIdx.x;
    int i = blockIdx.x * 1024 + tid;
    buf[tid] = (i < n) ? counts[i] : 0;
    __syncthreads();
#pragma unroll
    for (int off = 1; off < 1024; off <<= 1) {
        int t = (tid >= off) ? buf[tid - off] : 0;
        __syncthreads();
        buf[tid] += t;
        __syncthreads();
    }
    if (i < n) partial[i] = buf[tid];
    if (tid == 1023) blocksums[blockIdx.x] = buf[1023];
}

// ---------------- stage 2: single-wave inclusive scan of block sums (nb <= 64) ----
__global__ __launch_bounds__(64) void scan_carry(int* __restrict__ blocksums, int nb) {
    int tid = threadIdx.x;
    int v = (tid < nb) ? blocksums[tid] : 0;
#pragma unroll
    for (int off = 1; off < 64; off <<= 1) {
        int t = __shfl_up(v, off);
        if (tid >= off) v += t;
    }
    if (tid < nb) blocksums[tid] = v;
}

// ---------------- stage 3: add carry, emit offs[0..n] ----------------
__global__ __launch_bounds__(256) void scan_add(const int* __restrict__ partial,
                                                const int* __restrict__ blocksums,
                                                int* __restrict__ offs, int n) {
    int i = blockIdx.x * 256 + threadIdx.x;
    if (i >= n) return;
    int b = i >> 10;
    int carry = (b > 0) ? blocksums[b - 1] : 0;
    offs[i + 1] = partial[i] + carry;
    if (i == 0) offs[0] = 0;
}

// ---------------- scatter edges into CSR order ----------------
__global__ __launch_bounds__(256) void scatter_edges(
        const int* __restrict__ src, const int* __restrict__ dst,
        const int* __restrict__ etype, const float* __restrict__ norm,
        const int* __restrict__ offs, int* __restrict__ counts,
        int* __restrict__ ridx, float* __restrict__ rnorm, int E, int M) {
    int e = blockIdx.x * 256 + threadIdx.x;
    if (e >= E) return;
    int d = dst[e];
    int pos = offs[d] + atomicSub(&counts[d], 1) - 1;
    ridx[pos]  = etype[e] * M + src[e];
    rnorm[pos] = norm[e];
}

// ---------------- f32 -> bf16 convert ----------------
__global__ __launch_bounds__(256) void convert_bf16(const float* __restrict__ in,
                                                    unsigned short* __restrict__ out, int n4) {
    int i = blockIdx.x * 256 + threadIdx.x;
    if (i >= n4) return;
    float4 v = ((const float4*)in)[i];
    ushort4 o;
    o.x = f2bf(v.x); o.y = f2bf(v.y); o.z = f2bf(v.z); o.w = f2bf(v.w);
    ((ushort4*)out)[i] = o;
}

// ---------------- W^T build: Wt[l][r][o][d] = bf16(sum_b comp[r,b]*basis[b][d][o]) ----
__global__ __launch_bounds__(128) void make_wt(
        const float* __restrict__ basis0, const float* __restrict__ comp0,
        const float* __restrict__ basis1, const float* __restrict__ comp1,
        unsigned short* __restrict__ Wt) {
    int r = blockIdx.x;        // 0..7
    int d = blockIdx.y;        // 0..127
    int l = blockIdx.z;        // 0..1
    int o = threadIdx.x;       // 0..127
    const float* basis = l ? basis1 : basis0;
    const float* comp  = l ? comp1  : comp0;
    float s = 0.f;
#pragma unroll
    for (int b = 0; b < NB; ++b)
        s += comp[r * NB + b] * basis[((size_t)b * H + d) * H + o];
    Wt[(((size_t)l * NR + r) * H + o) * H + d] = f2bf(s);
}

// ---------------- MFMA GEMM: Hr[r] = h @ W_r, bf16 in/out, f32 accum ----------------
// grid (ceil(M/128), 8), block 256 (4 waves). Full K=128 staged once.
__global__ __launch_bounds__(256) void gemm_hr(
        const unsigned short* __restrict__ hbf,  // [M][128] bf16
        const unsigned short* __restrict__ Wt,   // [8][128 o][128 d] bf16
        unsigned short* __restrict__ Hr,         // [8][M][128] bf16
        int M) {
    __shared__ unsigned short lA[128 * 128];
    __shared__ unsigned short lB[128 * 128];
    const int m0  = blockIdx.x * 128;
    const int rel = blockIdx.y;
    const int tid = threadIdx.x;

    // stage A (h tile, swizzled rows)
#pragma unroll
    for (int i = 0; i < 8; ++i) {
        int idx = tid + i * 256;      // 0..2047
        int row = idx >> 4;           // 0..127
        int c   = idx & 15;           // 16B chunk
        int gm  = m0 + row;
        if (gm < M) {
            short8 v = *(const short8*)(hbf + (size_t)gm * H + c * 8);
            int byte = row * 256 + ((c * 16) ^ ((row & 7) << 4));
            *(short8*)((char*)lA + byte) = v;
        }
    }
    // stage B (Wt[rel], swizzled rows; row index = output col o)
    const unsigned short* Wr = Wt + (size_t)rel * H * H;
#pragma unroll
    for (int i = 0; i < 8; ++i) {
        int idx = tid + i * 256;
        int row = idx >> 4;
        int c   = idx & 15;
        short8 v = *(const short8*)(Wr + (size_t)row * H + c * 8);
        int byte = row * 256 + ((c * 16) ^ ((row & 7) << 4));
        *(short8*)((char*)lB + byte) = v;
    }
    __syncthreads();

    const int wid  = tid >> 6;
    const int lane = tid & 63;
    const int lr   = lane & 15;
    const int lg   = lane >> 4;

    f32x4 acc[2][8];
#pragma unroll
    for (int m = 0; m < 2; ++m)
#pragma unroll
        for (int n = 0; n < 8; ++n) acc[m][n] = (f32x4){0.f, 0.f, 0.f, 0.f};

#pragma unroll
    for (int s = 0; s < 4; ++s) {
        short8 a[2], b[8];
        int kb = s * 64 + lg * 16;
#pragma unroll
        for (int m = 0; m < 2; ++m) {
            int row = wid * 32 + m * 16 + lr;
            a[m] = *(const short8*)((const char*)lA + row * 256 + (kb ^ ((row & 7) << 4)));
        }
#pragma unroll
        for (int n = 0; n < 8; ++n) {
            int col = n * 16 + lr;
            b[n] = *(const short8*)((const char*)lB + col * 256 + (kb ^ ((col & 7) << 4)));
        }
#pragma unroll
        for (int m = 0; m < 2; ++m)
#pragma unroll
            for (int n = 0; n < 8; ++n)
                acc[m][n] = __builtin_amdgcn_mfma_f32_16x16x32_bf16(a[m], b[n], acc[m][n], 0, 0, 0);
    }

    unsigned short* C = Hr + (size_t)rel * M * H;
#pragma unroll
    for (int m = 0; m < 2; ++m) {
#pragma unroll
        for (int j = 0; j < 4; ++j) {
            int row = m0 + wid * 32 + m * 16 + lg * 4 + j;
            if (row < M) {
#pragma unroll
                for (int n = 0; n < 8; ++n) {
                    int col = n * 16 + lr;
                    C[(size_t)row * H + col] = f2bf(acc[m][n][j]);
                }
            }
        }
    }
}

// ---------------- per-node aggregation (CSR), fused bias+relu ----------------
// one wave per dst node; lane covers cols [2*lane, 2*lane+1]
__global__ __launch_bounds__(256) void agg_nodes(
        const unsigned short* __restrict__ Hr,   // rows indexed by ridx, 128 bf16 each
        const int* __restrict__ offs, const int* __restrict__ ridx,
        const float* __restrict__ rnorm, const float* __restrict__ bias,
        void* __restrict__ outp, int M, int write_bf16) {
    int v = blockIdx.x * 4 + (threadIdx.x >> 6);
    if (v >= M) return;
    int lane = threadIdx.x & 63;
    int beg = offs[v], end = offs[v + 1];

    float ax = 0.f, ay = 0.f;
    for (int base = beg; base < end; base += 64) {
        int cnt = min(64, end - base);
        int myrow = 0; float myw = 0.f;
        if (lane < cnt) { myrow = ridx[base + lane]; myw = rnorm[base + lane]; }
        int j = 0;
        for (; j + 4 <= cnt; j += 4) {
            int r0 = __shfl(myrow, j);     float w0 = __shfl(myw, j);
            int r1 = __shfl(myrow, j + 1); float w1 = __shfl(myw, j + 1);
            int r2 = __shfl(myrow, j + 2); float w2 = __shfl(myw, j + 2);
            int r3 = __shfl(myrow, j + 3); float w3 = __shfl(myw, j + 3);
            unsigned v0 = *(const unsigned*)(Hr + (size_t)r0 * H + lane * 2);
            unsigned v1 = *(const unsigned*)(Hr + (size_t)r1 * H + lane * 2);
            unsigned v2 = *(const unsigned*)(Hr + (size_t)r2 * H + lane * 2);
            unsigned v3 = *(const unsigned*)(Hr + (size_t)r3 * H + lane * 2);
            ax += w0 * bf_lo(v0); ay += w0 * bf_hi(v0);
            ax += w1 * bf_lo(v1); ay += w1 * bf_hi(v1);
            ax += w2 * bf_lo(v2); ay += w2 * bf_hi(v2);
            ax += w3 * bf_lo(v3); ay += w3 * bf_hi(v3);
        }
        for (; j < cnt; ++j) {
            int r0 = __shfl(myrow, j); float w0 = __shfl(myw, j);
            unsigned v0 = *(const unsigned*)(Hr + (size_t)r0 * H + lane * 2);
            ax += w0 * bf_lo(v0); ay += w0 * bf_hi(v0);
        }
    }
    ax = fmaxf(ax + bias[lane * 2],     0.f);
    ay = fmaxf(ay + bias[lane * 2 + 1], 0.f);
    if (write_bf16) {
        unsigned short* o = (unsigned short*)outp + (size_t)v * H + lane * 2;
        unsigned pk = (unsigned)f2bf(ax) | ((unsigned)f2bf(ay) << 16);
        *(unsigned*)o = pk;
    } else {
        float* o = (float*)outp + (size_t)v * H + lane * 2;
        *(float2*)o = make_float2(ax, ay);
    }
}

extern "C" void kernel_launch(void* const* d_in, const int* in_sizes, int n_in,
                              void* d_out, int out_size, void* d_ws, size_t ws_size,
                              hipStream_t stream) {
    const float* feats  = (const float*)d_in[0];
    const int*   src    = (const int*)  d_in[1];
    const int*   dst    = (const int*)  d_in[2];
    const int*   etype  = (const int*)  d_in[3];
    const float* norm   = (const float*)d_in[4];
    const float* basis0 = (const float*)d_in[5];
    const float* comp0  = (const float*)d_in[6];
    const float* bias0  = (const float*)d_in[7];
    const float* basis1 = (const float*)d_in[8];
    const float* comp1  = (const float*)d_in[9];
    const float* bias1  = (const float*)d_in[10];
    float* out = (float*)d_out;

    const int M = in_sizes[0] / H;     // 50000
    const int E = in_sizes[1];         // 600000

    // workspace carve-up (256B aligned)
    char* ws = (char*)d_ws;
    size_t cur = 0;
    auto take = [&](size_t bytes) { void* p = ws + cur; cur += (bytes + 255) & ~(size_t)255; return p; };
    unsigned short* Hr   = (unsigned short*)take((size_t)NR * M * H * 2);  // 102.4 MB
    unsigned short* hbf  = (unsigned short*)take((size_t)M * H * 2);       // 12.8 MB (feats bf16, then h1 bf16)
    unsigned short* Wt   = (unsigned short*)take((size_t)2 * NR * H * H * 2); // 512 KB
    int*   counts  = (int*)take((size_t)M * 4);
    int*   offs    = (int*)take((size_t)(M + 1) * 4);
    int*   partial = (int*)take((size_t)M * 4);
    int*   bsums   = (int*)take((size_t)64 * 4);
    int*   ridx    = (int*)take((size_t)E * 4);
    float* rnorm   = (float*)take((size_t)E * 4);

    dim3 blk(256);
    int mb  = (M + 255) / 256;
    int eb  = (E + 255) / 256;
    int n4  = M * H / 4;
    int cb  = (n4 + 255) / 256;
    int nsb = (M + 1023) / 1024;       // scan blocks (49 <= 64)
    dim3 gemm_grid((M + 127) / 128, NR);
    int agg_blocks = (M + 3) / 4;

    // ---- graph prep (stateless every call) ----
    zero_i       <<<mb, blk, 0, stream>>>(counts, M);
    hist_dst     <<<eb, blk, 0, stream>>>(dst, counts, E);
    scan_blocks  <<<nsb, 1024, 0, stream>>>(counts, partial, bsums, M);
    scan_carry   <<<1, 64, 0, stream>>>(bsums, nsb);
    scan_add     <<<mb, blk, 0, stream>>>(partial, bsums, offs, M);
    scatter_edges<<<eb, blk, 0, stream>>>(src, dst, etype, norm, offs, counts, ridx, rnorm, E, M);
    convert_bf16 <<<cb, blk, 0, stream>>>(feats, hbf, n4);
    make_wt      <<<dim3(NR, H, 2), 128, 0, stream>>>(basis0, comp0, basis1, comp1, Wt);

    // ---- layer 0 ----
    gemm_hr  <<<gemm_grid, blk, 0, stream>>>(hbf, Wt, Hr, M);
    agg_nodes<<<agg_blocks, blk, 0, stream>>>(Hr, offs, ridx, rnorm, bias0, hbf, M, 1);

    // ---- layer 1 ----
    gemm_hr  <<<gemm_grid, blk, 0, stream>>>(hbf, Wt + (size_t)NR * H * H, Hr, M);
    agg_nodes<<<agg_blocks, blk, 0, stream>>>(Hr, offs, ridx, rnorm, bias1, out, M, 0);
}